// Round 11
// baseline (1258.919 us; speedup 1.0000x reference)
//
#include <hip/hip_runtime.h>
#include <math.h>

#define NB 64
#define NQ 300
#define NP 6
#define ND 256
#define NF 512
#define NCL 396
#define NT 10
#define GRID 256

typedef float f4 __attribute__((ext_vector_type(4)));

__device__ __forceinline__ float dot4(f4 a, f4 b) {
    return a.x * b.x + a.y * b.y + a.z * b.z + a.w * b.w;
}
__device__ __forceinline__ float wred(float s) {
    #pragma unroll
    for (int o = 32; o; o >>= 1) s += __shfl_down(s, o, 64);
    return s;
}

// generation grid barrier: flags[0]=cnt, flags[16]=gen (separate lines)
__device__ __forceinline__ void gbar(int* flags, int tid) {
    __syncthreads();
    if (tid == 0) {
        __threadfence();
        int g = __hip_atomic_load(&flags[16], __ATOMIC_ACQUIRE, __HIP_MEMORY_SCOPE_AGENT);
        int prev = __hip_atomic_fetch_add(&flags[0], 1, __ATOMIC_ACQ_REL, __HIP_MEMORY_SCOPE_AGENT);
        if (prev == GRID - 1) {
            __hip_atomic_store(&flags[0], 0, __ATOMIC_RELAXED, __HIP_MEMORY_SCOPE_AGENT);
            __hip_atomic_fetch_add(&flags[16], 1, __ATOMIC_RELEASE, __HIP_MEMORY_SCOPE_AGENT);
        } else {
            while (__hip_atomic_load(&flags[16], __ATOMIC_ACQUIRE, __HIP_MEMORY_SCOPE_AGENT) == g)
                __builtin_amdgcn_s_sleep(4);
        }
        __threadfence();
    }
    __syncthreads();
}

__global__ void zero_kernel(int* flags) {
    if (threadIdx.x < 48) flags[threadIdx.x] = 0;
}

// ---------------------------------------------------------------------------
// Persistent mega-kernel: 256 blocks x 1024 threads, all phases separated by
// grid barriers. flags[32] is the pool work-stealing ticket.
// ---------------------------------------------------------------------------
__global__ __launch_bounds__(1024) void mega_kernel(
    const float* __restrict__ pred, const float* __restrict__ hs,
    const float* __restrict__ f0, const float* __restrict__ f1,
    const float* __restrict__ f2, const float* __restrict__ f3,
    const float* __restrict__ ipw, const float* __restrict__ ipb,
    const float* __restrict__ inw, const float* __restrict__ inb,
    const float* __restrict__ ow, const float* __restrict__ ob,
    const float* __restrict__ l1w, const float* __restrict__ l1b,
    const float* __restrict__ l2w, const float* __restrict__ l2b,
    const float* __restrict__ ln1w, const float* __restrict__ ln1b,
    const float* __restrict__ ln2w, const float* __restrict__ ln2b,
    const float* __restrict__ c1w, const float* __restrict__ c1b,
    const float* __restrict__ c2w, const float* __restrict__ c2b,
    float* __restrict__ pooled, float* __restrict__ tokG,
    float* __restrict__ biasW, float* __restrict__ qkvW,
    float* __restrict__ aoW, float* __restrict__ xBW,
    float* __restrict__ h1W, int* __restrict__ flags,
    float* __restrict__ out)
{
    const int blk = blockIdx.x;
    const int tid = threadIdx.x;
    const int lane = tid & 63;
    const int wv = tid >> 6;

    __shared__ __align__(16) float sh[16384];   // 64 KB
    const f4* sh4 = reinterpret_cast<const f4*>(sh);

    // ================= P0: cls-pool (blocks 0..63) =================
    if (blk < NB) {
        const int b = blk;
        float* maskL = sh;            // [1800]
        float* csum  = sh + 2048;     // [6144]
        float* cnts  = sh + 8300;     // [8]
        for (int i = tid; i < NQ * NP; i += 1024) {
            float x = pred[(size_t)b * NQ * NP + i];
            float sg = 1.f / (1.f + expf(-x));
            maskL[i] = (sg > 0.3f) ? 1.f : 0.f;
        }
        __syncthreads();
        if (wv < NP) {
            float c = 0.f;
            for (int q = lane; q < NQ; q += 64) c += maskL[q * NP + wv];
            c = wred(c);
            if (lane == 0) cnts[wv] = c;
        }
        {
            const int ty = tid >> 8, tx = tid & 255;
            float acc[NP] = {0.f, 0.f, 0.f, 0.f, 0.f, 0.f};
            const float* hsq = hs + ((size_t)b * NQ + ty * 75) * ND + tx;
            for (int q = 0; q < 75; q++) {
                float h = hsq[(size_t)q * ND];
                #pragma unroll
                for (int p = 0; p < NP; p++)
                    acc[p] += maskL[(ty * 75 + q) * NP + p] * h;
            }
            #pragma unroll
            for (int p = 0; p < NP; p++)
                csum[ty * 1536 + p * 256 + tx] = acc[p];
        }
        __syncthreads();
        bool anyv = (cnts[0] > 0.f) || (cnts[1] > 0.f) || (cnts[2] > 0.f)
                 || (cnts[3] > 0.f) || (cnts[4] > 0.f) || (cnts[5] > 0.f);
        for (int o = tid; o < NP * ND; o += 1024) {
            int p = o >> 8;
            float s = csum[o] + csum[1536 + o] + csum[3072 + o] + csum[4608 + o];
            float cm = s / fmaxf(cnts[p], 1.f);
            if (p == 0 && !anyv) cm = hs[(size_t)b * NQ * ND + (o & 255)];
            tokG[(size_t)b * 2560 + o] = cm;
        }
        if (tid < 16) {
            float bv = 0.f;
            if (tid < NP) {
                bool v = cnts[tid] > 0.f;
                if (tid == 0 && !anyv) v = true;
                bv = v ? 0.f : -1e30f;
            }
            biasW[b * 16 + tid] = bv;
        }
        __syncthreads();
    }

    // ================= P0: feat pooling, wave-level work stealing =================
    for (;;) {
        int t;
        if (lane == 0)
            t = __hip_atomic_fetch_add(&flags[32], 1, __ATOMIC_RELAXED, __HIP_MEMORY_SCOPE_AGENT);
        t = __shfl(t, 0, 64);
        if (t >= 4096) break;
        #pragma unroll 1
        for (int j = 0; j < 16; j++) {
            const int row = t * 16 + j;
            const int scale = row >> 14;
            const int rr = row & 16383;
            const int b = rr >> 8;
            const int d = rr & 255;
            const float* src;
            int n;
            switch (scale) {
                case 0: src = f0; n = 96 * 96; break;
                case 1: src = f1; n = 48 * 48; break;
                case 2: src = f2; n = 24 * 24; break;
                default: src = f3; n = 12 * 12; break;
            }
            const f4* p4 = reinterpret_cast<const f4*>(src + ((size_t)b * ND + d) * (size_t)n);
            const int n4 = n >> 2;
            float s = 0.f;
            for (int i = lane; i < n4; i += 64) {
                f4 v = __builtin_nontemporal_load(&p4[i]);
                s += v.x + v.y + v.z + v.w;
            }
            s = wred(s);
            if (lane == 0) pooled[((size_t)b * 4 + scale) * ND + d] = s / (float)n;
        }
    }
    gbar(flags, tid);

    // ================= P1: img proj: blk = (b, i) =================
    {
        const int b = blk >> 2, i = blk & 3;
        for (int o = tid; o < ND; o += 1024) sh[o] = pooled[((size_t)b * 4 + i) * ND + o];
        __syncthreads();
        const int c = tid & 255, ks = tid >> 8;
        const f4* w4 = reinterpret_cast<const f4*>(ipw + ((size_t)i * ND + c) * ND);
        float acc = 0.f;
        #pragma unroll 4
        for (int k4 = ks * 16; k4 < ks * 16 + 16; k4++) acc += dot4(w4[k4], sh4[k4]);
        sh[256 + ks * 256 + c] = acc;
        __syncthreads();
        if (tid < ND)
            tokG[(size_t)b * 2560 + (6 + i) * ND + tid] =
                sh[256 + tid] + sh[512 + tid] + sh[768 + tid] + sh[1024 + tid] + ipb[i * ND + tid];
    }
    gbar(flags, tid);

    for (int l = 0; l < 2; l++) {
        // ---- P2 QKV: blk = (b, quarter g of 768 cols => 192 cols) ----
        {
            const int b = blk >> 2, g = blk & 3;
            for (int i = tid; i < 2560; i += 1024) sh[i] = tokG[(size_t)b * 2560 + i];
            __syncthreads();
            float* pp = sh + 2560;   // [4][10][192] = 7680
            if (tid < 768) {
                const int cl = tid >> 2, ks = tid & 3;
                const int col = g * 192 + cl;
                const f4* w4 = reinterpret_cast<const f4*>(inw + ((size_t)l * 768 + col) * ND);
                float acc[NT];
                #pragma unroll
                for (int r = 0; r < NT; r++) acc[r] = 0.f;
                for (int k4 = ks * 16; k4 < ks * 16 + 16; k4++) {
                    f4 wvv = w4[k4];
                    #pragma unroll
                    for (int r = 0; r < NT; r++) acc[r] += dot4(wvv, sh4[r * 64 + k4]);
                }
                #pragma unroll
                for (int r = 0; r < NT; r++) pp[ks * 1920 + r * 192 + cl] = acc[r];
            }
            __syncthreads();
            for (int o = tid; o < 1920; o += 1024) {
                int r = o / 192, cl = o - r * 192;
                int col = g * 192 + cl;
                qkvW[(size_t)b * 7680 + r * 768 + col] =
                    pp[o] + pp[1920 + o] + pp[3840 + o] + pp[5760 + o] + inb[l * 768 + col];
            }
        }
        gbar(flags, tid);

        // ---- P3 attention: blk = (b, head-pair hp) ----
        {
            const int b = blk >> 2, h0 = (blk & 3) * 2;
            for (int i = tid; i < 1920; i += 1024) {
                int r = i / 192, cm = i - r * 192;
                int hh = cm / 96, cm2 = cm - hh * 96;
                int m = cm2 >> 5, c = cm2 & 31;
                sh[i] = qkvW[(size_t)b * 7680 + r * 768 + m * ND + (h0 + hh) * 32 + c];
            }
            __syncthreads();
            if (tid < 200) {
                int hh = tid / 100, rem = tid - hh * 100;
                int qr = rem / 10, kr = rem - qr * 10;
                const float* qp = &sh[qr * 192 + hh * 96];
                const float* kp = &sh[kr * 192 + hh * 96 + 32];
                float s = 0.f;
                #pragma unroll
                for (int dh = 0; dh < 32; dh++) s += qp[dh] * kp[dh];
                sh[1920 + hh * 100 + qr * 10 + kr] = s * 0.17677669529663687f + biasW[b * 16 + kr];
            }
            __syncthreads();
            if (tid < 20) {
                float* row = &sh[1920 + tid * 10];
                float m = row[0];
                #pragma unroll
                for (int k = 1; k < 10; k++) m = fmaxf(m, row[k]);
                float ss = 0.f;
                #pragma unroll
                for (int k = 0; k < 10; k++) { float e = expf(row[k] - m); row[k] = e; ss += e; }
                float inv = 1.f / ss;
                #pragma unroll
                for (int k = 0; k < 10; k++) row[k] *= inv;
            }
            __syncthreads();
            if (tid < 640) {
                int hh = tid / 320, rem = tid - hh * 320;
                int r = rem >> 5, c = rem & 31;
                float s = 0.f;
                #pragma unroll
                for (int kr = 0; kr < 10; kr++)
                    s += sh[1920 + hh * 100 + r * 10 + kr] * sh[kr * 192 + hh * 96 + 64 + c];
                aoW[(size_t)b * 2560 + r * ND + (h0 + hh) * 32 + c] = s;
            }
        }
        gbar(flags, tid);

        // ---- P4 out_proj + residual + LN1: blk < 64 = b ----
        if (blk < NB) {
            const int b = blk;
            for (int i = tid; i < 2560; i += 1024) {
                sh[i] = aoW[(size_t)b * 2560 + i];          // ao  [0..2560)
                sh[2560 + i] = tokG[(size_t)b * 2560 + i];  // x   [2560..5120)
            }
            __syncthreads();
            float* pp = sh + 5120;   // [4][10][256] = 10240 -> [5120..15360)
            {
                const int c = tid & 255, ks = tid >> 8;
                const f4* w4 = reinterpret_cast<const f4*>(ow + ((size_t)l * ND + c) * ND);
                float acc[NT];
                #pragma unroll
                for (int r = 0; r < NT; r++) acc[r] = 0.f;
                for (int k4 = ks * 16; k4 < ks * 16 + 16; k4++) {
                    f4 wvv = w4[k4];
                    #pragma unroll
                    for (int r = 0; r < NT; r++) acc[r] += dot4(wvv, sh4[r * 64 + k4]);
                }
                #pragma unroll
                for (int r = 0; r < NT; r++) pp[ks * 2560 + r * ND + c] = acc[r];
            }
            __syncthreads();
            for (int o = tid; o < 2560; o += 1024)
                sh[o] = sh[2560 + o] + pp[o] + pp[2560 + o] + pp[5120 + o] + pp[7680 + o]
                      + ob[l * ND + (o & 255)];
            __syncthreads();
            if (wv < NT) {
                const int r = wv;
                float v0 = sh[r * ND + lane], v1 = sh[r * ND + 64 + lane];
                float v2 = sh[r * ND + 128 + lane], v3 = sh[r * ND + 192 + lane];
                float s = wred(v0 + v1 + v2 + v3);
                float q = wred(v0 * v0 + v1 * v1 + v2 * v2 + v3 * v3);
                if (lane == 0) {
                    float m = s * (1.f / ND);
                    sh[15360 + r] = m;
                    sh[15376 + r] = rsqrtf(fmaxf(q * (1.f / ND) - m * m, 0.f) + 1e-5f);
                }
            }
            __syncthreads();
            for (int o = tid; o < 2560; o += 1024) {
                int r = o >> 8, c = o & 255;
                xBW[(size_t)b * 2560 + o] =
                    (sh[o] - sh[15360 + r]) * sh[15376 + r] * ln1w[l * ND + c] + ln1b[l * ND + c];
            }
        }
        gbar(flags, tid);

        // ---- P5 FF1: blk = (b, quarter g of 512 cols => 128 cols) ----
        {
            const int b = blk >> 2, g = blk & 3;
            for (int i = tid; i < 2560; i += 1024) sh[i] = xBW[(size_t)b * 2560 + i];
            __syncthreads();
            float* pp = sh + 2560;   // [8][10][128] = 10240 -> [2560..12800)
            {
                const int cl = tid >> 3, ks = tid & 7;
                const int col = g * 128 + cl;
                const f4* w4 = reinterpret_cast<const f4*>(l1w + ((size_t)l * NF + col) * ND);
                float acc[NT];
                #pragma unroll
                for (int r = 0; r < NT; r++) acc[r] = 0.f;
                for (int k4 = ks * 8; k4 < ks * 8 + 8; k4++) {
                    f4 wvv = w4[k4];
                    #pragma unroll
                    for (int r = 0; r < NT; r++) acc[r] += dot4(wvv, sh4[r * 64 + k4]);
                }
                #pragma unroll
                for (int r = 0; r < NT; r++) pp[ks * 1280 + r * 128 + cl] = acc[r];
            }
            __syncthreads();
            for (int o = tid; o < 1280; o += 1024) {
                int r = o >> 7, cl = o & 127;
                int col = g * 128 + cl;
                float s = pp[o] + pp[1280 + o] + pp[2560 + o] + pp[3840 + o]
                        + pp[5120 + o] + pp[6400 + o] + pp[7680 + o] + pp[8960 + o];
                h1W[(size_t)b * 5120 + r * NF + col] = fmaxf(s + l1b[l * NF + col], 0.f);
            }
        }
        gbar(flags, tid);

        // ---- P6 FF2 + residual + LN2: blk < 64 = b ----
        if (blk < NB) {
            const int b = blk;
            for (int i = tid; i < 5120; i += 1024) sh[i] = h1W[(size_t)b * 5120 + i];       // h1 [0..5120)
            for (int i = tid; i < 2560; i += 1024) sh[10240 + i] = xBW[(size_t)b * 2560 + i]; // xB [10240..12800)
            __syncthreads();
            float acc[NT];
            const int c = tid & 255, ks = tid >> 8;
            {
                const f4* w4 = reinterpret_cast<const f4*>(l2w + ((size_t)l * ND + c) * NF);
                #pragma unroll
                for (int r = 0; r < NT; r++) acc[r] = 0.f;
                for (int k4 = ks * 32; k4 < ks * 32 + 32; k4++) {
                    f4 wvv = w4[k4];
                    #pragma unroll
                    for (int r = 0; r < NT; r++) acc[r] += dot4(wvv, sh4[r * 128 + k4]);
                }
            }
            __syncthreads();            // h1 reads done; reuse [0..10240) for partials
            float* pp = sh;
            #pragma unroll
            for (int r = 0; r < NT; r++) pp[ks * 2560 + r * ND + c] = acc[r];
            __syncthreads();
            for (int o = tid; o < 2560; o += 1024)
                sh[12800 + o] = sh[10240 + o] + pp[o] + pp[2560 + o] + pp[5120 + o] + pp[7680 + o]
                              + l2b[l * ND + (o & 255)];
            __syncthreads();
            if (wv < NT) {
                const int r = wv;
                const float* xx = sh + 12800 + r * ND;
                float v0 = xx[lane], v1 = xx[64 + lane], v2 = xx[128 + lane], v3 = xx[192 + lane];
                float s = wred(v0 + v1 + v2 + v3);
                float q = wred(v0 * v0 + v1 * v1 + v2 * v2 + v3 * v3);
                if (lane == 0) {
                    float m = s * (1.f / ND);
                    sh[15360 + r] = m;
                    sh[15376 + r] = rsqrtf(fmaxf(q * (1.f / ND) - m * m, 0.f) + 1e-5f);
                }
            }
            __syncthreads();
            for (int o = tid; o < 2560; o += 1024) {
                int r = o >> 8, cc = o & 255;
                tokG[(size_t)b * 2560 + o] =
                    (sh[12800 + o] - sh[15360 + r]) * sh[15376 + r] * ln2w[l * ND + cc] + ln2b[l * ND + cc];
            }
        }
        gbar(flags, tid);
    }

    // ================= P7: masked mean pool + classifier: blk < 64 =================
    if (blk < NB) {
        const int b = blk;
        for (int i = tid; i < 2560; i += 1024) sh[i] = tokG[(size_t)b * 2560 + i];
        if (tid < 16) sh[2816 + tid] = biasW[b * 16 + tid];
        __syncthreads();
        if (tid < ND) {
            float len = 0.f, s = 0.f;
            #pragma unroll
            for (int r = 0; r < NT; r++) {
                float v = (sh[2816 + r] == 0.f) ? 1.f : 0.f;
                len += v;
                s += v * sh[r * ND + tid];
            }
            sh[2560 + tid] = s / fmaxf(len, 1.f);   // ct [2560..2816)
        }
        __syncthreads();
        {   // cls1: 512 cols x Ksplit2 -> pp [3072..4096)
            const int c = tid & 511, ks = tid >> 9;
            const f4* w4 = reinterpret_cast<const f4*>(c1w + (size_t)c * ND);
            const f4* ct4 = reinterpret_cast<const f4*>(sh + 2560);
            float acc = 0.f;
            #pragma unroll 4
            for (int k4 = ks * 32; k4 < ks * 32 + 32; k4++) acc += dot4(w4[k4], ct4[k4]);
            sh[3072 + ks * 512 + c] = acc;
        }
        __syncthreads();
        if (tid < 512)
            sh[4096 + tid] = fmaxf(sh[3072 + tid] + sh[3584 + tid] + c1b[tid], 0.f);  // h [4096..4608)
        __syncthreads();
        {   // cls2: 396 outputs x Ksplit2 -> pp2 [5120..6144)
            const int o = tid & 511, ks = tid >> 9;
            if (o < NCL) {
                const f4* w4 = reinterpret_cast<const f4*>(c2w + (size_t)o * NF);
                const f4* h4 = reinterpret_cast<const f4*>(sh + 4096);
                float acc = 0.f;
                #pragma unroll 4
                for (int k4 = ks * 64; k4 < ks * 64 + 64; k4++) acc += dot4(w4[k4], h4[k4]);
                sh[5120 + ks * 512 + o] = acc;
            }
        }
        __syncthreads();
        if (tid < NCL)
            out[(size_t)b * NCL + tid] = sh[5120 + tid] + sh[5632 + tid] + c2b[tid];
    }
}

// ---------------------------------------------------------------------------
extern "C" void kernel_launch(void* const* d_in, const int* in_sizes, int n_in,
                              void* d_out, int out_size, void* d_ws, size_t ws_size,
                              hipStream_t stream)
{
    const float* pred = (const float*)d_in[0];
    const float* hs   = (const float*)d_in[1];
    const float* f0   = (const float*)d_in[2];
    const float* f1   = (const float*)d_in[3];
    const float* f2   = (const float*)d_in[4];
    const float* f3   = (const float*)d_in[5];
    const float* ipw  = (const float*)d_in[6];
    const float* ipb  = (const float*)d_in[7];
    const float* inw  = (const float*)d_in[8];
    const float* inb  = (const float*)d_in[9];
    const float* ow   = (const float*)d_in[10];
    const float* ob   = (const float*)d_in[11];
    const float* l1w  = (const float*)d_in[12];
    const float* l1b  = (const float*)d_in[13];
    const float* l2w  = (const float*)d_in[14];
    const float* l2b  = (const float*)d_in[15];
    const float* ln1w = (const float*)d_in[16];
    const float* ln1b = (const float*)d_in[17];
    const float* ln2w = (const float*)d_in[18];
    const float* ln2b = (const float*)d_in[19];
    const float* c1w  = (const float*)d_in[20];
    const float* c1b  = (const float*)d_in[21];
    const float* c2w  = (const float*)d_in[22];
    const float* c2b  = (const float*)d_in[23];

    float* ws = (float*)d_ws;
    float* pooled = ws;                       //  65536
    float* tokG   = pooled + NB * 4 * ND;     // 163840
    float* biasW  = tokG + NB * NT * ND;      //   1024
    float* qkvW   = biasW + 1024;             // 491520
    float* aoW    = qkvW + NB * NT * 768;     // 163840
    float* xBW    = aoW + NB * NT * ND;       // 163840
    float* h1W    = xBW + NB * NT * ND;       // 327680
    int*   flags  = (int*)(h1W + NB * NT * NF); //  48 ints

    zero_kernel<<<1, 64, 0, stream>>>(flags);
    mega_kernel<<<GRID, 1024, 0, stream>>>(
        pred, hs, f0, f1, f2, f3, ipw, ipb, inw, inb, ow, ob,
        l1w, l1b, l2w, l2b, ln1w, ln1b, ln2w, ln2b, c1w, c1b, c2w, c2b,
        pooled, tokG, biasW, qkvW, aoW, xBW, h1W, flags, (float*)d_out);
}

// Round 12
// 418.943 us; speedup vs baseline: 3.0050x; 3.0050x over previous
//
#include <hip/hip_runtime.h>
#include <math.h>

#define NB 64
#define NQ 300
#define NP 6
#define ND 256
#define NF 512
#define NCL 396
#define NT 10

// transposed-weight workspace offsets (floats)
#define IPT_OFF 0           // [4][256k][256c]   262144
#define INT_OFF 262144      // [2][256k][768c]   393216
#define OWT_OFF 655360      // [2][256k][256c]   131072
#define L1T_OFF 786432      // [2][256k][512c]   262144
#define L2T_OFF 1048576     // [2][512k][256c]   262144
#define C1T_OFF 1310720     // [256k][512c]      131072
#define C2T_OFF 1441792     // [512k][396c]      202752
#define NTILES  408
#define POOL_ROWS 65536

typedef float f4 __attribute__((ext_vector_type(4)));
typedef float f2 __attribute__((ext_vector_type(2)));

__device__ __forceinline__ float wred(float s) {
    #pragma unroll
    for (int o = 32; o; o >>= 1) s += __shfl_down(s, o, 64);
    return s;
}

// ---------------------------------------------------------------------------
// K1: blocks 0..63                -> per-class masked mean pool + bias
//     blocks 64..64+65535         -> feat global-average-pool rows
//     blocks 64+65536..+NTILES    -> weight transpose (64x64 LDS tiles)
// ---------------------------------------------------------------------------
__global__ __launch_bounds__(256) void pool_cls_kernel(
    const float* __restrict__ pred, const float* __restrict__ hs,
    const float* __restrict__ f0, const float* __restrict__ f1,
    const float* __restrict__ f2w, const float* __restrict__ f3,
    const float* __restrict__ ipw, const float* __restrict__ inw,
    const float* __restrict__ ow, const float* __restrict__ l1w,
    const float* __restrict__ l2w, const float* __restrict__ c1w,
    const float* __restrict__ c2w,
    float* __restrict__ pooled, float* __restrict__ tokG,
    float* __restrict__ biasW, float* __restrict__ wT)
{
    const int bid = blockIdx.x;
    const int tid = threadIdx.x;
    __shared__ float shm[64 * 65];   // transpose tile; cls uses first 1824+

    if (bid < NB) {
        const int b = bid;
        float* maskL = shm;
        float* countsL = shm + 1800;
        for (int i = tid; i < NQ * NP; i += 256) {
            float x = pred[(size_t)b * NQ * NP + i];
            float sg = 1.f / (1.f + expf(-x));
            maskL[i] = (sg > 0.3f) ? 1.f : 0.f;
        }
        __syncthreads();
        if (tid < NP) {
            float c = 0.f;
            for (int q = 0; q < NQ; q++) c += maskL[q * NP + tid];
            countsL[tid] = c;
        }
        __syncthreads();
        float acc[NP] = {0.f, 0.f, 0.f, 0.f, 0.f, 0.f};
        const float* hsb = hs + (size_t)b * NQ * ND + tid;
        for (int q = 0; q < NQ; q++) {
            float h = hsb[(size_t)q * ND];
            #pragma unroll
            for (int p = 0; p < NP; p++) acc[p] += maskL[q * NP + p] * h;
        }
        bool anyv = false;
        #pragma unroll
        for (int p = 0; p < NP; p++) anyv = anyv || (countsL[p] > 0.f);
        #pragma unroll
        for (int p = 0; p < NP; p++) {
            float cm = acc[p] / fmaxf(countsL[p], 1.f);
            if (p == 0 && !anyv) cm = hs[(size_t)b * NQ * ND + tid];
            tokG[(size_t)b * 1536 + p * ND + tid] = cm;
        }
        if (tid < 16) {
            float bv = 0.f;
            if (tid < NP) {
                bool v = countsL[tid] > 0.f;
                if (tid == 0 && !anyv) v = true;
                bv = v ? 0.f : -1e30f;
            }
            biasW[b * 16 + tid] = bv;
        }
        return;
    }

    if (bid >= NB + POOL_ROWS) {
        // -------- weight transpose: one 64x64 tile per block --------
        const int idx = bid - (NB + POOL_ROWS);
        const float* s; float* d; int C, K, tile;
        if (idx < 64)       { int m = idx >> 4;  tile = idx & 15;          s = ipw + (size_t)m * 65536;  d = wT + IPT_OFF + (size_t)m * 65536;  C = 256; K = 256; }
        else if (idx < 160) { int q = idx - 64;  int m = q / 48; tile = q % 48; s = inw + (size_t)m * 196608; d = wT + INT_OFF + (size_t)m * 196608; C = 768; K = 256; }
        else if (idx < 192) { int q = idx - 160; int m = q >> 4; tile = q & 15; s = ow + (size_t)m * 65536;   d = wT + OWT_OFF + (size_t)m * 65536;  C = 256; K = 256; }
        else if (idx < 256) { int q = idx - 192; int m = q >> 5; tile = q & 31; s = l1w + (size_t)m * 131072; d = wT + L1T_OFF + (size_t)m * 131072; C = 512; K = 256; }
        else if (idx < 320) { int q = idx - 256; int m = q >> 5; tile = q & 31; s = l2w + (size_t)m * 131072; d = wT + L2T_OFF + (size_t)m * 131072; C = 256; K = 512; }
        else if (idx < 352) { tile = idx - 320; s = c1w; d = wT + C1T_OFF; C = 512; K = 256; }
        else                { tile = idx - 352; s = c2w; d = wT + C2T_OFF; C = 396; K = 512; }
        const int CT = (C + 63) >> 6;
        const int ct = tile % CT, kt = tile / CT;
        const int c0 = ct * 64, k0 = kt * 64;
        const int li = tid >> 6, lj = tid & 63;
        #pragma unroll 4
        for (int rep = 0; rep < 16; rep++) {
            int i = rep * 4 + li;               // c-direction
            if (c0 + i < C) shm[i * 65 + lj] = s[(size_t)(c0 + i) * K + k0 + lj];
        }
        __syncthreads();
        #pragma unroll 4
        for (int rep = 0; rep < 16; rep++) {
            int j = rep * 4 + li;               // k-direction
            int cc = c0 + lj;
            if (cc < C) d[(size_t)(k0 + j) * C + cc] = shm[lj * 65 + j];
        }
        return;
    }

    // -------- feature pooling --------
    const int row = bid - NB;
    const int scale = row >> 14;
    const int rr = row & 16383;
    const int b = rr >> 8;
    const int dd = rr & 255;
    const float* src;
    int n;
    switch (scale) {
        case 0: src = f0; n = 96 * 96; break;
        case 1: src = f1; n = 48 * 48; break;
        case 2: src = f2w; n = 24 * 24; break;
        default: src = f3; n = 12 * 12; break;
    }
    const f4* p4 = reinterpret_cast<const f4*>(src + ((size_t)b * ND + dd) * (size_t)n);
    int n4 = n >> 2;
    float s = 0.f;
    for (int i = tid; i < n4; i += 256) {
        f4 v = __builtin_nontemporal_load(&p4[i]);
        s += v.x + v.y + v.z + v.w;
    }
    s = wred(s);
    int wid = tid >> 6, lane = tid & 63;
    if (lane == 0) shm[wid] = s;
    __syncthreads();
    if (tid == 0) {
        float t = shm[0] + shm[1] + shm[2] + shm[3];
        pooled[((size_t)b * 4 + scale) * ND + dd] = t / (float)n;
    }
}

// ---------------------------------------------------------------------------
// K2: fused per-batch transformer with K-major (transposed) weights.
// 64 blocks x 1024 threads. All weight loads coalesced: lane c reads
// Wt[k][c..], consecutive lanes -> consecutive addresses.
// ---------------------------------------------------------------------------
__global__ __launch_bounds__(1024) void xform_kernel(
    const float* __restrict__ pooled, const float* __restrict__ tokG,
    const float* __restrict__ biasW, const float* __restrict__ wT,
    const float* __restrict__ ipb, const float* __restrict__ inb,
    const float* __restrict__ ob, const float* __restrict__ l1b,
    const float* __restrict__ l2b,
    const float* __restrict__ n1w, const float* __restrict__ n1b,
    const float* __restrict__ n2w, const float* __restrict__ n2b,
    const float* __restrict__ c1b, const float* __restrict__ c2b,
    float* __restrict__ out)
{
    const int b = blockIdx.x;
    const int tid = threadIdx.x;
    const int lane = tid & 63;
    const int wv = tid >> 6;

    __shared__ __align__(16) float xs[NT * ND];    // 2560 current x
    __shared__ __align__(16) float xr[NT * ND];    // 2560 q / resid
    __shared__ __align__(16) float kv[NT * 512];   // 5120 k|v / gemm accum scratch
    __shared__ __align__(16) float big[NT * NF];   // 5120 pld / ao+sc / h1 / epilogue
    __shared__ float stats[32];
    __shared__ float biasK[16];

    // ---------------- stage ----------------
    for (int i = tid; i < 1536; i += 1024) xs[i] = tokG[(size_t)b * 1536 + i];
    big[tid] = pooled[(size_t)b * 1024 + tid];     // pld
    if (tid < 16) biasK[tid] = biasW[b * 16 + tid];
    __syncthreads();

    // ---- img tokens: thread (i = tid>>8, c = tid&255), coalesced Wt ----
    {
        const int i = tid >> 8, c = tid & 255;
        const float* w = wT + IPT_OFF + (size_t)i * 65536 + c;
        const float* x = &big[i * 256];
        float acc = 0.f;
        #pragma unroll 4
        for (int k = 0; k < 256; k++) acc += w[(size_t)k * 256] * x[k];
        __syncthreads();
        xs[(6 + i) * 256 + c] = acc + ipb[i * 256 + c];
    }
    __syncthreads();

    for (int l = 0; l < 2; l++) {
        // ---- (a) QKV: 192 f4-col owners x Ksplit4 (768 thr) ----
        {
            f4 acc[NT];
            #pragma unroll
            for (int r = 0; r < NT; r++) acc[r] = (f4){0.f, 0.f, 0.f, 0.f};
            const bool act = tid < 768;
            const int ks = tid / 192, cg = tid % 192;
            if (act) {
                const float* wbase = wT + INT_OFF + (size_t)l * 196608 + (size_t)(ks * 64) * 768 + 4 * cg;
                for (int kk = 0; kk < 64; kk++) {
                    f4 w4 = *reinterpret_cast<const f4*>(wbase + (size_t)kk * 768);
                    const int k = ks * 64 + kk;
                    #pragma unroll
                    for (int r = 0; r < NT; r++) {
                        float xv = xs[r * 256 + k];
                        acc[r] += w4 * xv;
                    }
                }
            }
            #pragma unroll 1
            for (int p = 0; p < 4; p++) {
                if (act && ks == p) {
                    const int c0 = 4 * cg;
                    #pragma unroll
                    for (int r = 0; r < NT; r++) {
                        #pragma unroll
                        for (int j = 0; j < 4; j++) {
                            int c = c0 + j;
                            float v = acc[r][j];
                            float* dst = (c < 256) ? &xr[r * 256 + c] : &kv[r * 512 + (c - 256)];
                            if (p == 0) *dst = v + inb[l * 768 + c];
                            else        *dst += v;
                        }
                    }
                }
                __syncthreads();
            }
        }

        // ---- (b) scores + bias (q in xr, k in kv) ----
        if (tid < 800) {
            int h = tid / 100, rem = tid - 100 * h;
            int qr = rem / 10, kr = rem - 10 * qr;
            const float* qp = &xr[qr * 256 + h * 32];
            const float* kp = &kv[kr * 512 + h * 32];
            float s = 0.f;
            #pragma unroll
            for (int dh = 0; dh < 32; dh++) s += qp[dh] * kp[dh];
            big[2560 + tid] = s * 0.17677669529663687f + biasK[kr];
        }
        __syncthreads();

        // ---- (c) softmax ----
        if (tid < 80) {
            float* row = &big[2560 + tid * 10];
            float m = row[0];
            #pragma unroll
            for (int k = 1; k < 10; k++) m = fmaxf(m, row[k]);
            float ss = 0.f;
            #pragma unroll
            for (int k = 0; k < 10; k++) { float e = expf(row[k] - m); row[k] = e; ss += e; }
            float inv = 1.f / ss;
            #pragma unroll
            for (int k = 0; k < 10; k++) row[k] *= inv;
        }
        __syncthreads();

        // ---- (d) attn @ V -> ao in big[0..2560) ----
        for (int idx = tid; idx < 2560; idx += 1024) {
            int r = idx >> 8, col = idx & 255, h = col >> 5;
            float s = 0.f;
            #pragma unroll
            for (int kr = 0; kr < 10; kr++)
                s += big[2560 + h * 100 + r * 10 + kr] * kv[kr * 512 + 256 + col];
            big[idx] = s;
        }
        __syncthreads();

        // ---- (e) out_proj: 128 f2-col owners x Ksplit4 (512 thr) -> kv[0..2560) ----
        {
            float a0[NT], a1[NT];
            #pragma unroll
            for (int r = 0; r < NT; r++) { a0[r] = 0.f; a1[r] = 0.f; }
            const bool act = tid < 512;
            const int ks = tid >> 7, cg = tid & 127;
            if (act) {
                const float* wbase = wT + OWT_OFF + (size_t)l * 65536 + (size_t)(ks * 64) * 256 + 2 * cg;
                for (int kk = 0; kk < 64; kk++) {
                    f2 w2 = *reinterpret_cast<const f2*>(wbase + (size_t)kk * 256);
                    const int k = ks * 64 + kk;
                    #pragma unroll
                    for (int r = 0; r < NT; r++) {
                        float av = big[r * 256 + k];
                        a0[r] += w2.x * av;
                        a1[r] += w2.y * av;
                    }
                }
            }
            #pragma unroll 1
            for (int p = 0; p < 4; p++) {
                if (act && ks == p) {
                    const int c = 2 * cg;
                    #pragma unroll
                    for (int r = 0; r < NT; r++) {
                        if (p == 0) {
                            kv[r * 256 + c]     = a0[r] + ob[l * 256 + c];
                            kv[r * 256 + c + 1] = a1[r] + ob[l * 256 + c + 1];
                        } else {
                            kv[r * 256 + c]     += a0[r];
                            kv[r * 256 + c + 1] += a1[r];
                        }
                    }
                }
                __syncthreads();
            }
        }
        for (int i = tid; i < 2560; i += 1024) xr[i] = xs[i] + kv[i];
        __syncthreads();

        // ---- (f) LN1: xr -> xs ----
        if (wv < NT) {
            const int r = wv;
            float v0 = xr[r * 256 + lane], v1 = xr[r * 256 + 64 + lane];
            float v2 = xr[r * 256 + 128 + lane], v3 = xr[r * 256 + 192 + lane];
            float s = wred(v0 + v1 + v2 + v3);
            float q = wred(v0 * v0 + v1 * v1 + v2 * v2 + v3 * v3);
            if (lane == 0) {
                float m = s * (1.f / 256.f);
                stats[r] = m;
                stats[16 + r] = rsqrtf(fmaxf(q * (1.f / 256.f) - m * m, 0.f) + 1e-5f);
            }
        }
        __syncthreads();
        for (int i = tid; i < 2560; i += 1024) {
            int r = i >> 8, c = i & 255;
            xs[i] = (xr[i] - stats[r]) * stats[16 + r] * n1w[l * 256 + c] + n1b[l * 256 + c];
        }
        __syncthreads();

        // ---- (g) FF1: 256 f2-col owners x Ksplit4 (1024 thr) -> big[0..5120) ----
        {
            float a0[NT], a1[NT];
            #pragma unroll
            for (int r = 0; r < NT; r++) { a0[r] = 0.f; a1[r] = 0.f; }
            const int ks = tid >> 8, cg = tid & 255;
            const float* wbase = wT + L1T_OFF + (size_t)l * 131072 + (size_t)(ks * 64) * 512 + 2 * cg;
            for (int kk = 0; kk < 64; kk++) {
                f2 w2 = *reinterpret_cast<const f2*>(wbase + (size_t)kk * 512);
                const int k = ks * 64 + kk;
                #pragma unroll
                for (int r = 0; r < NT; r++) {
                    float xv = xs[r * 256 + k];
                    a0[r] += w2.x * xv;
                    a1[r] += w2.y * xv;
                }
            }
            #pragma unroll 1
            for (int p = 0; p < 4; p++) {
                if (ks == p) {
                    const int c = 2 * cg;
                    #pragma unroll
                    for (int r = 0; r < NT; r++) {
                        if (p == 0) {
                            big[r * 512 + c]     = a0[r] + l1b[l * 512 + c];
                            big[r * 512 + c + 1] = a1[r] + l1b[l * 512 + c + 1];
                        } else {
                            big[r * 512 + c]     += a0[r];
                            big[r * 512 + c + 1] += a1[r];
                        }
                    }
                }
                __syncthreads();
            }
            for (int i = tid; i < 5120; i += 1024) big[i] = fmaxf(big[i], 0.f);
            __syncthreads();
        }

        // ---- (h) FF2: 128 f2-col owners x Ksplit4 over K=512 (512 thr) -> kv ----
        {
            float a0[NT], a1[NT];
            #pragma unroll
            for (int r = 0; r < NT; r++) { a0[r] = 0.f; a1[r] = 0.f; }
            const bool act = tid < 512;
            const int ks = tid >> 7, cg = tid & 127;
            if (act) {
                const float* wbase = wT + L2T_OFF + (size_t)l * 131072 + (size_t)(ks * 128) * 256 + 2 * cg;
                for (int kk = 0; kk < 128; kk++) {
                    f2 w2 = *reinterpret_cast<const f2*>(wbase + (size_t)kk * 256);
                    const int k = ks * 128 + kk;
                    #pragma unroll
                    for (int r = 0; r < NT; r++) {
                        float hv = big[r * 512 + k];
                        a0[r] += w2.x * hv;
                        a1[r] += w2.y * hv;
                    }
                }
            }
            #pragma unroll 1
            for (int p = 0; p < 4; p++) {
                if (act && ks == p) {
                    const int c = 2 * cg;
                    #pragma unroll
                    for (int r = 0; r < NT; r++) {
                        if (p == 0) {
                            kv[r * 256 + c]     = a0[r] + l2b[l * 256 + c];
                            kv[r * 256 + c + 1] = a1[r] + l2b[l * 256 + c + 1];
                        } else {
                            kv[r * 256 + c]     += a0[r];
                            kv[r * 256 + c + 1] += a1[r];
                        }
                    }
                }
                __syncthreads();
            }
        }
        for (int i = tid; i < 2560; i += 1024) xr[i] = xs[i] + kv[i];
        __syncthreads();

        // ---- (i) LN2: xr -> xs ----
        if (wv < NT) {
            const int r = wv;
            float v0 = xr[r * 256 + lane], v1 = xr[r * 256 + 64 + lane];
            float v2 = xr[r * 256 + 128 + lane], v3 = xr[r * 256 + 192 + lane];
            float s = wred(v0 + v1 + v2 + v3);
            float q = wred(v0 * v0 + v1 * v1 + v2 * v2 + v3 * v3);
            if (lane == 0) {
                float m = s * (1.f / 256.f);
                stats[r] = m;
                stats[16 + r] = rsqrtf(fmaxf(q * (1.f / 256.f) - m * m, 0.f) + 1e-5f);
            }
        }
        __syncthreads();
        for (int i = tid; i < 2560; i += 1024) {
            int r = i >> 8, c = i & 255;
            xs[i] = (xr[i] - stats[r]) * stats[16 + r] * n2w[l * 256 + c] + n2b[l * 256 + c];
        }
        __syncthreads();
    }

    // ---------------- epilogue ----------------
    // masked mean pool -> big[0..256)
    if (tid < 256) {
        float len = 0.f, s = 0.f;
        #pragma unroll
        for (int r = 0; r < NT; r++) {
            float v = (biasK[r] == 0.f) ? 1.f : 0.f;
            len += v;
            s += v * xs[r * 256 + tid];
        }
        big[tid] = s / fmaxf(len, 1.f);
    }
    __syncthreads();

    // cls1: 256 f2-col owners x Ksplit2 (512 thr) -> big[512..1024)
    {
        float a0 = 0.f, a1 = 0.f;
        const bool act = tid < 512;
        const int ks = tid >> 8, cg = tid & 255;
        if (act) {
            const float* wbase = wT + C1T_OFF + (size_t)(ks * 128) * 512 + 2 * cg;
            #pragma unroll 4
            for (int kk = 0; kk < 128; kk++) {
                f2 w2 = *reinterpret_cast<const f2*>(wbase + (size_t)kk * 512);
                float xv = big[ks * 128 + kk];
                a0 += w2.x * xv;
                a1 += w2.y * xv;
            }
        }
        #pragma unroll 1
        for (int p = 0; p < 2; p++) {
            if (act && ks == p) {
                const int c = 2 * cg;
                if (p == 0) {
                    big[512 + c]     = a0 + c1b[c];
                    big[512 + c + 1] = a1 + c1b[c + 1];
                } else {
                    big[512 + c]     += a0;
                    big[512 + c + 1] += a1;
                }
            }
            __syncthreads();
        }
        if (tid < 512) big[512 + tid] = fmaxf(big[512 + tid], 0.f);
        __syncthreads();
    }

    // cls2: 396 scalar owners x Ksplit2
    {
        const int o = tid & 511, ks = tid >> 9;
        float acc = 0.f;
        const bool act = o < NCL;
        if (act) {
            const float* wbase = wT + C2T_OFF + (size_t)(ks * 256) * 396 + o;
            #pragma unroll 4
            for (int kk = 0; kk < 256; kk++)
                acc += wbase[(size_t)kk * 396] * big[512 + ks * 256 + kk];
        }
        if (act && ks == 0) big[1536 + o] = acc;
        __syncthreads();
        if (act && ks == 1) out[(size_t)b * NCL + o] = big[1536 + o] + acc + c2b[o];
    }
}

// ---------------------------------------------------------------------------
extern "C" void kernel_launch(void* const* d_in, const int* in_sizes, int n_in,
                              void* d_out, int out_size, void* d_ws, size_t ws_size,
                              hipStream_t stream)
{
    const float* pred = (const float*)d_in[0];
    const float* hs   = (const float*)d_in[1];
    const float* f0   = (const float*)d_in[2];
    const float* f1   = (const float*)d_in[3];
    const float* f2i  = (const float*)d_in[4];
    const float* f3   = (const float*)d_in[5];
    const float* ipw  = (const float*)d_in[6];
    const float* ipb  = (const float*)d_in[7];
    const float* inw  = (const float*)d_in[8];
    const float* inb  = (const float*)d_in[9];
    const float* ow   = (const float*)d_in[10];
    const float* ob   = (const float*)d_in[11];
    const float* l1w  = (const float*)d_in[12];
    const float* l1b  = (const float*)d_in[13];
    const float* l2w  = (const float*)d_in[14];
    const float* l2b  = (const float*)d_in[15];
    const float* ln1w = (const float*)d_in[16];
    const float* ln1b = (const float*)d_in[17];
    const float* ln2w = (const float*)d_in[18];
    const float* ln2b = (const float*)d_in[19];
    const float* c1w  = (const float*)d_in[20];
    const float* c1b  = (const float*)d_in[21];
    const float* c2w  = (const float*)d_in[22];
    const float* c2b  = (const float*)d_in[23];

    float* ws = (float*)d_ws;
    float* pooled = ws;                    //   65536
    float* tokG   = pooled + NB * 4 * ND;  //   98304
    float* biasW  = tokG + NB * 1536;      //    1024
    float* wT     = biasW + 1024;          // 1644544

    pool_cls_kernel<<<NB + POOL_ROWS + NTILES, 256, 0, stream>>>(
        pred, hs, f0, f1, f2i, f3, ipw, inw, ow, l1w, l2w, c1w, c2w,
        pooled, tokG, biasW, wT);
    xform_kernel<<<NB, 1024, 0, stream>>>(
        pooled, tokG, biasW, wT, ipb, inb, ob, l1b, l2b,
        ln1w, ln1b, ln2w, ln2b, c1b, c2b, (float*)d_out);
}

// Round 13
// 345.296 us; speedup vs baseline: 3.6459x; 1.2133x over previous
//
#include <hip/hip_runtime.h>
#include <hip/hip_fp16.h>
#include <math.h>

#define NB 64
#define NQ 300
#define NP 6
#define ND 256
#define NF 512
#define NCL 396
#define NT 10

// fp16 weight workspace layout (element offsets in halves) — R10 layout
#define IPW_OFF 0
#define INW_OFF 262144
#define OW_OFF  655360
#define L1W_OFF 786432
#define L2W_OFF 1048576
#define C1W_OFF 1310720
#define C2W_OFF 1441792
#define TOTW    1644544
#define CONV_BLOCKS 803
#define POOL_ROWS 65536

typedef float f4 __attribute__((ext_vector_type(4)));

__device__ __forceinline__ float wred(float s) {
    #pragma unroll
    for (int o = 32; o; o >>= 1) s += __shfl_down(s, o, 64);
    return s;
}

__device__ __forceinline__ float dot8h(f4 wv, f4 xlo, f4 xhi) {
    const __half2* hp = reinterpret_cast<const __half2*>(&wv);
    float2 p0 = __half22float2(hp[0]);
    float2 p1 = __half22float2(hp[1]);
    float2 p2 = __half22float2(hp[2]);
    float2 p3 = __half22float2(hp[3]);
    return p0.x * xlo.x + p0.y * xlo.y + p1.x * xlo.z + p1.y * xlo.w
         + p2.x * xhi.x + p2.y * xhi.y + p3.x * xhi.z + p3.y * xhi.w;
}

// 4-sibling spin barrier (device scope; flags zeroed by K1 each call).
__device__ __forceinline__ void qsync(int* flag, int tid) {
    __syncthreads();
    if (tid == 0) {
        __threadfence();
        __hip_atomic_fetch_add(flag, 1, __ATOMIC_ACQ_REL, __HIP_MEMORY_SCOPE_AGENT);
        while (__hip_atomic_load(flag, __ATOMIC_ACQUIRE, __HIP_MEMORY_SCOPE_AGENT) < 4)
            __builtin_amdgcn_s_sleep(2);
    }
    __syncthreads();
}

// ---------------------------------------------------------------------------
// K1: blocks 0..63          -> cls masked-mean pool + bias (+ zero sync flags)
//     blocks 64..64+65535   -> feat pooling
//     rest                  -> f32 -> fp16 weight conversion
// ---------------------------------------------------------------------------
__global__ __launch_bounds__(256) void pool_cls_kernel(
    const float* __restrict__ pred, const float* __restrict__ hs,
    const float* __restrict__ f0, const float* __restrict__ f1,
    const float* __restrict__ f2, const float* __restrict__ f3,
    const float* __restrict__ ipw, const float* __restrict__ inw,
    const float* __restrict__ ow, const float* __restrict__ l1w,
    const float* __restrict__ l2w, const float* __restrict__ c1w,
    const float* __restrict__ c2w,
    float* __restrict__ pooled, float* __restrict__ tokG,
    float* __restrict__ biasW, __half* __restrict__ wH,
    int* __restrict__ flagW)
{
    const int bid = blockIdx.x;
    const int tid = threadIdx.x;
    __shared__ float shm[1824];

    if (bid < NB) {
        const int b = bid;
        if (tid < 16) flagW[b * 16 + tid] = 0;
        float* maskL = shm;
        float* countsL = shm + 1800;
        for (int i = tid; i < NQ * NP; i += 256) {
            float x = pred[(size_t)b * NQ * NP + i];
            float sg = 1.f / (1.f + expf(-x));
            maskL[i] = (sg > 0.3f) ? 1.f : 0.f;
        }
        __syncthreads();
        if (tid < NP) {
            float c = 0.f;
            for (int q = 0; q < NQ; q++) c += maskL[q * NP + tid];
            countsL[tid] = c;
        }
        __syncthreads();
        float acc[NP] = {0.f, 0.f, 0.f, 0.f, 0.f, 0.f};
        const float* hsb = hs + (size_t)b * NQ * ND + tid;
        for (int q = 0; q < NQ; q++) {
            float h = hsb[(size_t)q * ND];
            #pragma unroll
            for (int p = 0; p < NP; p++) acc[p] += maskL[q * NP + p] * h;
        }
        bool anyv = false;
        #pragma unroll
        for (int p = 0; p < NP; p++) anyv = anyv || (countsL[p] > 0.f);
        #pragma unroll
        for (int p = 0; p < NP; p++) {
            float cm = acc[p] / fmaxf(countsL[p], 1.f);
            if (p == 0 && !anyv) cm = hs[(size_t)b * NQ * ND + tid];
            tokG[(size_t)b * 2560 + p * ND + tid] = cm;
        }
        if (tid < 16) {
            float bv = 0.f;
            if (tid < NP) {
                bool v = countsL[tid] > 0.f;
                if (tid == 0 && !anyv) v = true;
                bv = v ? 0.f : -1e30f;
            }
            biasW[b * 16 + tid] = bv;
        }
        return;
    }

    if (bid >= NB + POOL_ROWS) {
        const int cid = bid - (NB + POOL_ROWS);
        size_t base = (size_t)cid * 2048 + (size_t)tid * 8;
        const float* src; size_t off;
        if      (base < INW_OFF) { src = ipw; off = IPW_OFF; }
        else if (base < OW_OFF)  { src = inw; off = INW_OFF; }
        else if (base < L1W_OFF) { src = ow;  off = OW_OFF;  }
        else if (base < L2W_OFF) { src = l1w; off = L1W_OFF; }
        else if (base < C1W_OFF) { src = l2w; off = L2W_OFF; }
        else if (base < C2W_OFF) { src = c1w; off = C1W_OFF; }
        else                     { src = c2w; off = C2W_OFF; }
        const f4* s4 = reinterpret_cast<const f4*>(src + (base - off));
        f4 a = s4[0], b2 = s4[1];
        union { __half2 h[4]; f4 v; } u;
        u.h[0] = __floats2half2_rn(a.x, a.y);
        u.h[1] = __floats2half2_rn(a.z, a.w);
        u.h[2] = __floats2half2_rn(b2.x, b2.y);
        u.h[3] = __floats2half2_rn(b2.z, b2.w);
        *reinterpret_cast<f4*>(wH + base) = u.v;
        return;
    }

    const int row = bid - NB;
    const int scale = row >> 14;
    const int rr = row & 16383;
    const int b = rr >> 8;
    const int d = rr & 255;
    const float* src;
    int n;
    switch (scale) {
        case 0: src = f0; n = 96 * 96; break;
        case 1: src = f1; n = 48 * 48; break;
        case 2: src = f2; n = 24 * 24; break;
        default: src = f3; n = 12 * 12; break;
    }
    const f4* p4 = reinterpret_cast<const f4*>(src + ((size_t)b * ND + d) * (size_t)n);
    int n4 = n >> 2;
    float s = 0.f;
    for (int i = tid; i < n4; i += 256) {
        f4 v = __builtin_nontemporal_load(&p4[i]);
        s += v.x + v.y + v.z + v.w;
    }
    s = wred(s);
    int wid = tid >> 6, lane = tid & 63;
    if (lane == 0) shm[wid] = s;
    __syncthreads();
    if (tid == 0) {
        float t = shm[0] + shm[1] + shm[2] + shm[3];
        pooled[((size_t)b * 4 + scale) * ND + d] = t / (float)n;
    }
}

// ---------------------------------------------------------------------------
// K2: column-split transformer. 256 blocks = (batch b, quarter qt) x 512 thr.
// Sibling qt owns heads {2qt,2qt+1}: its 64-col slice of q,k,v,ao; 64-col
// slice of out_proj/FF2 outputs; 128-col slice of FF1/cls1. Cross-sibling
// exchange via workspace + qsync only where K spans full width.
// ---------------------------------------------------------------------------
__global__ __launch_bounds__(512) void xform_kernel(
    const float* __restrict__ pooled, float* tokG,
    const float* __restrict__ biasW, const __half* __restrict__ wH,
    const float* __restrict__ ipb, const float* __restrict__ inb,
    const float* __restrict__ ob, const float* __restrict__ l1b,
    const float* __restrict__ l2b,
    const float* __restrict__ n1w, const float* __restrict__ n1b,
    const float* __restrict__ n2w, const float* __restrict__ n2b,
    const float* __restrict__ c1b, const float* __restrict__ c2b,
    float* aoW, float* resW, float* h1W, float* hW,
    int* flagW, float* __restrict__ out)
{
    const int b  = blockIdx.x >> 2;
    const int qt = blockIdx.x & 3;
    const int tid = threadIdx.x;
    const int lane = tid & 63;
    const int wv = tid >> 6;
    int* flags = flagW + b * 16;

    __shared__ __align__(16) float xs[2560];    // full current x
    __shared__ __align__(16) float loc[1920];   // own q|k|v slice
    __shared__ __align__(16) float buf[5120];   // pld / staged ao|resid|h1 / ct,h
    __shared__ __align__(16) float part[5120];  // K-split partials
    __shared__ float sc[224];
    __shared__ float stats[32];
    __shared__ float biasK[16];

    const f4* xs4 = reinterpret_cast<const f4*>(xs);
    const f4* buf4 = reinterpret_cast<const f4*>(buf);

    // ---------------- stage rows 0..5, pld, biasK ----------------
    for (int i = tid; i < 1536; i += 512) xs[i] = tokG[(size_t)b * 2560 + i];
    for (int i = tid; i < 1024; i += 512) buf[i] = pooled[(size_t)b * 1024 + i];
    if (tid < 16) biasK[tid] = biasW[b * 16 + tid];
    __syncthreads();

    // ---- P0 img-proj: own 64 cols x 4 scales ----
    if (tid < 256) {
        const int i = tid >> 6, cl = tid & 63;
        const int c = qt * 64 + cl;
        const f4* w4 = reinterpret_cast<const f4*>(wH + IPW_OFF + ((size_t)(i * 256 + c)) * 256);
        float acc = 0.f;
        #pragma unroll 4
        for (int k8 = 0; k8 < 32; k8++)
            acc += dot8h(w4[k8], buf4[i * 64 + 2 * k8], buf4[i * 64 + 2 * k8 + 1]);
        tokG[(size_t)b * 2560 + (6 + i) * 256 + c] = acc + ipb[i * 256 + c];
    }
    qsync(&flags[0], tid);
    for (int i = tid + 1536; i < 2560; i += 512) xs[i] = tokG[(size_t)b * 2560 + i];
    __syncthreads();

    for (int l = 0; l < 2; l++) {
        // ---- P1 QKV own 192 cols, Ksplit2 (384 thr) ----
        if (tid < 384) {
            const int ks = tid / 192, cl = tid % 192;
            const int m = cl >> 6;
            const int gc = m * 256 + qt * 64 + (cl & 63);
            const f4* w4 = reinterpret_cast<const f4*>(wH + INW_OFF + ((size_t)l * 768 + gc) * 256 + ks * 128);
            float acc[NT];
            #pragma unroll
            for (int r = 0; r < NT; r++) acc[r] = 0.f;
            for (int k8 = 0; k8 < 16; k8++) {
                f4 wv4 = w4[k8];
                const int xi = ks * 32 + 2 * k8;
                #pragma unroll
                for (int r = 0; r < NT; r++)
                    acc[r] += dot8h(wv4, xs4[r * 64 + xi], xs4[r * 64 + xi + 1]);
            }
            #pragma unroll
            for (int r = 0; r < NT; r++) part[ks * 1920 + r * 192 + cl] = acc[r];
        }
        __syncthreads();
        for (int i = tid; i < 1920; i += 512) {
            int r = i / 192, cl = i - r * 192;
            int m = cl >> 6, gc = m * 256 + qt * 64 + (cl & 63);
            loc[i] = part[i] + part[1920 + i] + inb[l * 768 + gc];
        }
        __syncthreads();

        // ---- P2 scores (2 own heads) ----
        if (tid < 200) {
            int hl = tid / 100, rem = tid - 100 * hl;
            int qr = rem / 10, kr = rem - 10 * qr;
            const float* qp = &loc[qr * 192 + hl * 32];
            const float* kp = &loc[kr * 192 + 64 + hl * 32];
            float s = 0.f;
            #pragma unroll
            for (int d = 0; d < 32; d++) s += qp[d] * kp[d];
            sc[tid] = s * 0.17677669529663687f + biasK[kr];
        }
        __syncthreads();
        if (tid < 20) {
            float* row = &sc[tid * 10];
            float m = row[0];
            #pragma unroll
            for (int k = 1; k < 10; k++) m = fmaxf(m, row[k]);
            float ss = 0.f;
            #pragma unroll
            for (int k = 0; k < 10; k++) { float e = expf(row[k] - m); row[k] = e; ss += e; }
            float inv = 1.f / ss;
            #pragma unroll
            for (int k = 0; k < 10; k++) row[k] *= inv;
        }
        __syncthreads();

        // ---- P3 AV -> own 64 ao cols -> aoW ----
        for (int idx = tid; idx < 640; idx += 512) {
            int hl = idx / 320, rem = idx - 320 * hl;
            int r = rem >> 5, c = rem & 31;
            float s = 0.f;
            #pragma unroll
            for (int kr = 0; kr < 10; kr++)
                s += sc[hl * 100 + r * 10 + kr] * loc[kr * 192 + 128 + hl * 32 + c];
            aoW[(size_t)b * 2560 + r * 256 + qt * 64 + hl * 32 + c] = s;
        }
        qsync(&flags[1 + l * 4], tid);
        for (int i = tid; i < 2560; i += 512) buf[i] = aoW[(size_t)b * 2560 + i];
        __syncthreads();

        // ---- P4 out_proj own 64 cols, Ksplit4 (256 thr) ----
        if (tid < 256) {
            const int ks = tid >> 6, cl = tid & 63;
            const int gc = qt * 64 + cl;
            const f4* w4 = reinterpret_cast<const f4*>(wH + OW_OFF + ((size_t)l * 256 + gc) * 256 + ks * 64);
            float acc[NT];
            #pragma unroll
            for (int r = 0; r < NT; r++) acc[r] = 0.f;
            for (int k8 = 0; k8 < 8; k8++) {
                f4 wv4 = w4[k8];
                const int xi = ks * 16 + 2 * k8;
                #pragma unroll
                for (int r = 0; r < NT; r++)
                    acc[r] += dot8h(wv4, buf4[r * 64 + xi], buf4[r * 64 + xi + 1]);
            }
            #pragma unroll
            for (int r = 0; r < NT; r++) part[ks * 640 + r * 64 + cl] = acc[r];
        }
        __syncthreads();
        for (int i = tid; i < 640; i += 512) {
            int r = i >> 6, cl = i & 63, gc = qt * 64 + cl;
            float v = part[i] + part[640 + i] + part[1280 + i] + part[1920 + i]
                    + ob[l * 256 + gc] + xs[r * 256 + gc];
            resW[(size_t)b * 2560 + r * 256 + gc] = v;
        }
        qsync(&flags[2 + l * 4], tid);
        for (int i = tid; i < 2560; i += 512) buf[i] = resW[(size_t)b * 2560 + i];
        __syncthreads();

        // ---- LN1 (redundant full) ----
        for (int r = wv; r < NT; r += 8) {
            float v0 = buf[r * 256 + lane], v1 = buf[r * 256 + 64 + lane];
            float v2 = buf[r * 256 + 128 + lane], v3 = buf[r * 256 + 192 + lane];
            float s = wred(v0 + v1 + v2 + v3);
            float q = wred(v0 * v0 + v1 * v1 + v2 * v2 + v3 * v3);
            if (lane == 0) {
                float m = s * (1.f / 256.f);
                stats[r] = m;
                stats[16 + r] = rsqrtf(fmaxf(q * (1.f / 256.f) - m * m, 0.f) + 1e-5f);
            }
        }
        __syncthreads();
        for (int i = tid; i < 2560; i += 512) {
            int r = i >> 8, c = i & 255;
            xs[i] = (buf[i] - stats[r]) * stats[16 + r] * n1w[l * 256 + c] + n1b[l * 256 + c];
        }
        __syncthreads();

        // ---- P5 FF1 own 128 cols, Ksplit4 (512 thr) -> buf as partials ----
        {
            const int ks = tid >> 7, cl = tid & 127;
            const int gc = qt * 128 + cl;
            const f4* w4 = reinterpret_cast<const f4*>(wH + L1W_OFF + ((size_t)l * 512 + gc) * 256 + ks * 64);
            float acc[NT];
            #pragma unroll
            for (int r = 0; r < NT; r++) acc[r] = 0.f;
            for (int k8 = 0; k8 < 8; k8++) {
                f4 wv4 = w4[k8];
                const int xi = ks * 16 + 2 * k8;
                #pragma unroll
                for (int r = 0; r < NT; r++)
                    acc[r] += dot8h(wv4, xs4[r * 64 + xi], xs4[r * 64 + xi + 1]);
            }
            __syncthreads();   // buf (resid) dead
            #pragma unroll
            for (int r = 0; r < NT; r++) buf[ks * 1280 + r * 128 + cl] = acc[r];
        }
        __syncthreads();
        for (int i = tid; i < 1280; i += 512) {
            int r = i >> 7, cl = i & 127, gc = qt * 128 + cl;
            float h = fmaxf(buf[i] + buf[1280 + i] + buf[2560 + i] + buf[3840 + i]
                          + l1b[l * 512 + gc], 0.f);
            h1W[(size_t)b * 5120 + r * 512 + gc] = h;
        }
        qsync(&flags[3 + l * 4], tid);
        for (int i = tid; i < 5120; i += 512) buf[i] = h1W[(size_t)b * 5120 + i];
        __syncthreads();

        // ---- P6 FF2 own 64 cols, Ksplit8 (512 thr) ----
        {
            const int ks = tid >> 6, cl = tid & 63;
            const int gc = qt * 64 + cl;
            const f4* w4 = reinterpret_cast<const f4*>(wH + L2W_OFF + ((size_t)l * 256 + gc) * 512 + ks * 64);
            float acc[NT];
            #pragma unroll
            for (int r = 0; r < NT; r++) acc[r] = 0.f;
            for (int k8 = 0; k8 < 8; k8++) {
                f4 wv4 = w4[k8];
                const int xi = ks * 16 + 2 * k8;
                #pragma unroll
                for (int r = 0; r < NT; r++)
                    acc[r] += dot8h(wv4, buf4[r * 128 + xi], buf4[r * 128 + xi + 1]);
            }
            #pragma unroll
            for (int r = 0; r < NT; r++) part[ks * 640 + r * 64 + cl] = acc[r];
        }
        __syncthreads();
        for (int i = tid; i < 640; i += 512) {
            int r = i >> 6, cl = i & 63, gc = qt * 64 + cl;
            float v = part[i] + part[640 + i] + part[1280 + i] + part[1920 + i]
                    + part[2560 + i] + part[3200 + i] + part[3840 + i] + part[4480 + i]
                    + l2b[l * 256 + gc] + xs[r * 256 + gc];
            resW[(size_t)b * 2560 + r * 256 + gc] = v;
        }
        qsync(&flags[4 + l * 4], tid);
        for (int i = tid; i < 2560; i += 512) buf[i] = resW[(size_t)b * 2560 + i];
        __syncthreads();

        // ---- LN2 (redundant full) ----
        for (int r = wv; r < NT; r += 8) {
            float v0 = buf[r * 256 + lane], v1 = buf[r * 256 + 64 + lane];
            float v2 = buf[r * 256 + 128 + lane], v3 = buf[r * 256 + 192 + lane];
            float s = wred(v0 + v1 + v2 + v3);
            float q = wred(v0 * v0 + v1 * v1 + v2 * v2 + v3 * v3);
            if (lane == 0) {
                float m = s * (1.f / 256.f);
                stats[r] = m;
                stats[16 + r] = rsqrtf(fmaxf(q * (1.f / 256.f) - m * m, 0.f) + 1e-5f);
            }
        }
        __syncthreads();
        for (int i = tid; i < 2560; i += 512) {
            int r = i >> 8, c = i & 255;
            xs[i] = (buf[i] - stats[r]) * stats[16 + r] * n2w[l * 256 + c] + n2b[l * 256 + c];
        }
        __syncthreads();
    }

    // ---------------- epilogue ----------------
    // masked mean pool (redundant) -> buf[0..256)
    if (tid < 256) {
        float len = 0.f, s = 0.f;
        #pragma unroll
        for (int r = 0; r < NT; r++) {
            float v = (biasK[r] == 0.f) ? 1.f : 0.f;
            len += v;
            s += v * xs[r * 256 + tid];
        }
        buf[tid] = s / fmaxf(len, 1.f);
    }
    __syncthreads();

    // cls1 own 128 cols, Ksplit2 (256 thr)
    if (tid < 256) {
        const int ks = tid >> 7, cl = tid & 127;
        const int gc = qt * 128 + cl;
        const f4* w4 = reinterpret_cast<const f4*>(wH + C1W_OFF + (size_t)gc * 256 + ks * 128);
        float acc = 0.f;
        #pragma unroll 4
        for (int k8 = 0; k8 < 16; k8++)
            acc += dot8h(w4[k8], buf4[ks * 32 + 2 * k8], buf4[ks * 32 + 2 * k8 + 1]);
        part[ks * 128 + cl] = acc;
    }
    __syncthreads();
    if (tid < 128) {
        const int gc = qt * 128 + tid;
        hW[(size_t)b * 512 + gc] = fmaxf(part[tid] + part[128 + tid] + c1b[gc], 0.f);
    }
    qsync(&flags[9], tid);
    for (int i = tid; i < 512; i += 512) buf[i] = hW[(size_t)b * 512 + i];
    __syncthreads();

    // cls2 own 99 outputs, full K=512
    if (tid < 99) {
        const int o = qt * 99 + tid;
        const f4* w4 = reinterpret_cast<const f4*>(wH + C2W_OFF + (size_t)o * 512);
        float acc = 0.f;
        #pragma unroll 4
        for (int k8 = 0; k8 < 64; k8++)
            acc += dot8h(w4[k8], buf4[2 * k8], buf4[2 * k8 + 1]);
        out[(size_t)b * NCL + o] = acc + c2b[o];
    }
}

// ---------------------------------------------------------------------------
extern "C" void kernel_launch(void* const* d_in, const int* in_sizes, int n_in,
                              void* d_out, int out_size, void* d_ws, size_t ws_size,
                              hipStream_t stream)
{
    const float* pred = (const float*)d_in[0];
    const float* hs   = (const float*)d_in[1];
    const float* f0   = (const float*)d_in[2];
    const float* f1   = (const float*)d_in[3];
    const float* f2   = (const float*)d_in[4];
    const float* f3   = (const float*)d_in[5];
    const float* ipw  = (const float*)d_in[6];
    const float* ipb  = (const float*)d_in[7];
    const float* inw  = (const float*)d_in[8];
    const float* inb  = (const float*)d_in[9];
    const float* ow   = (const float*)d_in[10];
    const float* ob   = (const float*)d_in[11];
    const float* l1w  = (const float*)d_in[12];
    const float* l1b  = (const float*)d_in[13];
    const float* l2w  = (const float*)d_in[14];
    const float* l2b  = (const float*)d_in[15];
    const float* ln1w = (const float*)d_in[16];
    const float* ln1b = (const float*)d_in[17];
    const float* ln2w = (const float*)d_in[18];
    const float* ln2b = (const float*)d_in[19];
    const float* c1w  = (const float*)d_in[20];
    const float* c1b  = (const float*)d_in[21];
    const float* c2w  = (const float*)d_in[22];
    const float* c2b  = (const float*)d_in[23];

    float* ws = (float*)d_ws;
    float* pooled = ws;                          //  65536
    float* tokG   = pooled + NB * 4 * ND;        // 163840 ([64][10][256])
    float* biasW  = tokG + NB * 2560;            //   1024
    __half* wH    = (__half*)(biasW + 1024);     // 1644544 halves = 822272 f
    float* aoW    = (float*)(wH + TOTW);         // 163840
    float* resW   = aoW + NB * 2560;             // 163840
    float* h1W    = resW + NB * 2560;            // 327680
    float* hW     = h1W + NB * 5120;             //  32768
    int*   flagW  = (int*)(hW + NB * 512);       //   1024 ints

    pool_cls_kernel<<<NB + POOL_ROWS + CONV_BLOCKS, 256, 0, stream>>>(
        pred, hs, f0, f1, f2, f3, ipw, inw, ow, l1w, l2w, c1w, c2w,
        pooled, tokG, biasW, wH, flagW);
    xform_kernel<<<4 * NB, 512, 0, stream>>>(
        pooled, tokG, biasW, wH, ipb, inb, ob, l1b, l2b,
        ln1w, ln1b, ln2w, ln2b, c1b, c2b,
        aoW, resW, h1W, hW, flagW, (float*)d_out);
}